// Round 13
// baseline (122.855 us; speedup 1.0000x reference)
//
#include <hip/hip_runtime.h>
#include <stdint.h>

#define EPS 1e-3f

typedef __bf16 bf16x8 __attribute__((ext_vector_type(8)));
typedef float  f32x4  __attribute__((ext_vector_type(4)));

static __device__ __forceinline__ uint16_t f2bf(float f) {
  union { __bf16 b; uint16_t u; } r; r.b = (__bf16)f; return r.u;
}
static __device__ __forceinline__ uint32_t cvt2(float lo, float hi) {
  union { __bf16 b[2]; uint32_t u; } r;
  r.b[0] = (__bf16)lo; r.b[1] = (__bf16)hi;
  return r.u;
}
static __device__ __forceinline__ void gload_lds16(const void* g, void* l) {
  __builtin_amdgcn_global_load_lds(
      (const __attribute__((address_space(1))) unsigned int*)g,
      (__attribute__((address_space(3))) unsigned int*)l, 16, 0, 0);
}

template <int J0>
static __device__ __forceinline__ void mfma2(const bf16x8 (&areg)[8], bf16x8 b0,
                                             bf16x8 b1, f32x4 (&acc)[8][4]) {
  __builtin_amdgcn_s_setprio(1);
#pragma unroll
  for (int i = 0; i < 8; ++i)
    acc[i][J0] = __builtin_amdgcn_mfma_f32_16x16x32_bf16(areg[i], b0, acc[i][J0], 0, 0, 0);
#pragma unroll
  for (int i = 0; i < 8; ++i)
    acc[i][J0 + 1] = __builtin_amdgcn_mfma_f32_16x16x32_bf16(areg[i], b1, acc[i][J0 + 1], 0, 0, 0);
  __builtin_amdgcn_s_setprio(0);
}

// ---------------------------------------------------------------------------
// Kernel 1: E convert+transpose (+ W prep on blocks < 144).
// ---------------------------------------------------------------------------
__global__ __launch_bounds__(256) void econv(
    const float* __restrict__ E, uint16_t* __restrict__ Ebf,
    const float* __restrict__ Wq, const float* __restrict__ Wk,
    const float* __restrict__ Wv, uint16_t* __restrict__ WtP)
{
  __shared__ uint16_t lds[1024 * 20 + 8];
  const int n = blockIdx.x, t = threadIdx.x;
  if (n < 144) {
    const int col = n;
    float val = (col < 64) ? Wq[t * 64 + col]
              : (col < 80) ? Wk[t * 16 + (col - 64)]
                           : Wv[t * 64 + (col - 80)];
    WtP[col * 264 + t] = f2bf(val);
  }
  const float* En = E + (size_t)n * 16384;
#pragma unroll
  for (int i = 0; i < 16; ++i) {
    int f4 = i * 256 + t;
    float4 d = *(const float4*)(En + (size_t)f4 * 4);
    int m = f4 >> 2, k0 = (f4 & 3) * 4;
    uint2 w; w.x = cvt2(d.x, d.y); w.y = cvt2(d.z, d.w);
    *(uint2*)&lds[m * 20 + k0] = w;
  }
  __syncthreads();
  const int k = t & 15, mg = t >> 4;
  uint16_t* dst = Ebf + (size_t)(n * 16 + k) * 1024 + mg * 64;
  const uint16_t* src = lds + (mg * 64) * 20 + k;
#pragma unroll
  for (int s = 0; s < 8; ++s) {
    union { uint16_t u[8]; uint4 q; } pk;
#pragma unroll
    for (int j = 0; j < 8; ++j) pk.u[j] = src[(s * 8 + j) * 20];
    *(uint4*)(dst + s * 8) = pk.q;
  }
}

// ---------------------------------------------------------------------------
// Kernel 2: MFMA projections + BN + softmax + V-transpose + lam_c partial.
// ---------------------------------------------------------------------------
__global__ __launch_bounds__(256) void proj_mfma(
    const float* __restrict__ x, const uint16_t* __restrict__ WtP,
    const float* __restrict__ gq, const float* __restrict__ bq,
    const float* __restrict__ mq, const float* __restrict__ vq,
    const float* __restrict__ gv, const float* __restrict__ bv,
    const float* __restrict__ mv, const float* __restrict__ vvp,
    float* __restrict__ Qf, uint16_t* __restrict__ VbfT,
    float* __restrict__ part)
{
  __shared__ __align__(16) char smem[111616];
  uint16_t* const xA = (uint16_t*)smem;         // [64][264] bf16
  char* const Wt = smem + 33792;                // [144][264] bf16

  const int t = threadIdx.x;
  const int wid = t >> 6, lane = t & 63;
  const int bid = blockIdx.x;
  const int b = bid >> 4, mc = bid & 15;
  const int r0 = b * 1024 + mc * 64;

#pragma unroll
  for (int i = 0; i < 19; ++i) {
    int off = (i * 256 + t) * 16;
    gload_lds16((const char*)WtP + off, Wt + off);
  }
  {
    const int row = t >> 2, ks0 = (t & 3) * 64;
    const float* src = x + (size_t)(r0 + row) * 256 + ks0;
    uint16_t* dstp = xA + row * 264 + ks0;
#pragma unroll
    for (int i = 0; i < 8; ++i) {
      float4 d0 = *(const float4*)(src + i * 8);
      float4 d1 = *(const float4*)(src + i * 8 + 4);
      uint4 q;
      q.x = cvt2(d0.x, d0.y); q.y = cvt2(d0.z, d0.w);
      q.z = cvt2(d1.x, d1.y); q.w = cvt2(d1.z, d1.w);
      *(uint4*)(dstp + i * 8) = q;
    }
  }
  __syncthreads();

  f32x4 acc[9];
#pragma unroll
  for (int f = 0; f < 9; ++f) acc[f] = f32x4{0.f, 0.f, 0.f, 0.f};
  const int arow = wid * 16 + (lane & 15);
#pragma unroll
  for (int kst = 0; kst < 8; ++kst) {
    const int sb = kst * 64 + ((lane >> 4) << 4);
    bf16x8 af = *(const bf16x8*)((const char*)xA + arow * 528 + sb);
#pragma unroll
    for (int f = 0; f < 9; ++f) {
      const int crow = f * 16 + (lane & 15);
      bf16x8 bfr = *(const bf16x8*)(Wt + crow * 528 + sb);
      acc[f] = __builtin_amdgcn_mfma_f32_16x16x32_bf16(af, bfr, acc[f], 0, 0, 0);
    }
  }

  const int cl = lane & 15;
  const int rbase = wid * 16 + ((lane >> 4) << 2);

  float qs[4], qb[4], qm[4], vs[4], vb[4], vm[4];
#pragma unroll
  for (int f = 0; f < 4; ++f) {
    const int c = f * 16 + cl;
    qs[f] = gq[c] * rsqrtf(vq[c] + EPS); qb[f] = bq[c]; qm[f] = mq[c];
    vs[f] = gv[c] * rsqrtf(vvp[c] + EPS); vb[f] = bv[c]; vm[f] = mv[c];
  }
#pragma unroll
  for (int f = 0; f < 4; ++f)
#pragma unroll
    for (int r = 0; r < 4; ++r)
      Qf[(size_t)(r0 + rbase + r) * 64 + f * 16 + cl] =
          (acc[f][r] - qm[f]) * qs[f] + qb[f];
  float ex[4];
#pragma unroll
  for (int r = 0; r < 4; ++r) {
    float kv = acc[4][r];
    float mx = kv;
#pragma unroll
    for (int d = 1; d < 16; d <<= 1) mx = fmaxf(mx, __shfl_xor(mx, d, 64));
    float e = __expf(kv - mx);
    float sm = e;
#pragma unroll
    for (int d = 1; d < 16; d <<= 1) sm += __shfl_xor(sm, d, 64);
    ex[r] = e / sm;
  }
  float vv[4][4];
#pragma unroll
  for (int f = 0; f < 4; ++f)
#pragma unroll
    for (int r = 0; r < 4; ++r)
      vv[f][r] = (acc[5 + f][r] - vm[f]) * vs[f] + vb[f];

  __syncthreads();
  float* const vt = (float*)smem;                 // [64][65] f32
  float* const ks = (float*)(smem + 64 * 65 * 4); // [64][20] f32
#pragma unroll
  for (int r = 0; r < 4; ++r) ks[(rbase + r) * 20 + cl] = ex[r];
#pragma unroll
  for (int f = 0; f < 4; ++f)
#pragma unroll
    for (int r = 0; r < 4; ++r) vt[(rbase + r) * 65 + f * 16 + cl] = vv[f][r];
  __syncthreads();

  {
    const int v = t & 63, grp = t >> 6;
#pragma unroll
    for (int h = 0; h < 2; ++h) {
      uint4 q;
      q.x = cvt2(vt[(grp * 16 + h * 8 + 0) * 65 + v], vt[(grp * 16 + h * 8 + 1) * 65 + v]);
      q.y = cvt2(vt[(grp * 16 + h * 8 + 2) * 65 + v], vt[(grp * 16 + h * 8 + 3) * 65 + v]);
      q.z = cvt2(vt[(grp * 16 + h * 8 + 4) * 65 + v], vt[(grp * 16 + h * 8 + 5) * 65 + v]);
      q.w = cvt2(vt[(grp * 16 + h * 8 + 6) * 65 + v], vt[(grp * 16 + h * 8 + 7) * 65 + v]);
      *(uint4*)&VbfT[(size_t)(b * 64 + v) * 1024 + mc * 64 + grp * 16 + h * 8] = q;
    }
  }
  {
    const int kq = t >> 6, v = t & 63;
    float a0 = 0.f, a1 = 0.f, a2 = 0.f, a3 = 0.f;
#pragma unroll 4
    for (int m = 0; m < 64; ++m) {
      float vvx = vt[m * 65 + v];
      a0 = fmaf(ks[m * 20 + kq * 4 + 0], vvx, a0);
      a1 = fmaf(ks[m * 20 + kq * 4 + 1], vvx, a1);
      a2 = fmaf(ks[m * 20 + kq * 4 + 2], vvx, a2);
      a3 = fmaf(ks[m * 20 + kq * 4 + 3], vvx, a3);
    }
    float* dst = part + ((size_t)(b * 16 + mc) << 10) + (kq * 4) * 64 + v;
    dst[0] = a0; dst[64] = a1; dst[128] = a2; dst[192] = a3;
  }
}

// Kernel 3: reduce 16 partials -> Lc[b][k][v]
__global__ __launch_bounds__(256) void lamc_reduce(const float* __restrict__ part,
                                                   float* __restrict__ Lc)
{
  const int gid = blockIdx.x * 256 + threadIdx.x;
  const int b = gid >> 10, r = gid & 1023;
  const float* p = part + ((size_t)b << 14) + r;
  float s = 0.f;
#pragma unroll
  for (int mc = 0; mc < 16; ++mc) s += p[mc << 10];
  Lc[((size_t)b << 10) + r] = s;
}

// ---------------------------------------------------------------------------
// Kernel 4: GEMM + fused epilogue — 8-phase schedule WITH READ-AHEAD:
// each phase: vmcnt(8) -> barrier -> ISSUE 1 half-tile -> ds_read NEXT
// phase's fragments (alternate reg set) -> MFMA current fragments.
// ds_read latency hides under MFMAs (m196/m201 interleave). Lc folded
// into acc init. Steady vmcnt(8) (slot-lifetime derived); tail vmcnt(0).
// ---------------------------------------------------------------------------
__global__ __launch_bounds__(512, 1) void gemm_out(
    const uint16_t* __restrict__ Ebf,   // [16384][1024]
    const uint16_t* __restrict__ VbfT,  // [1024][1024]
    const float* __restrict__ Qf,       // [16384][64]
    const float* __restrict__ Lc,       // [16][16][64]
    float* __restrict__ out)            // [16384][256]
{
  __shared__ __align__(16) char smem[131072];
  const int t = threadIdx.x;
  const int wid = t >> 6, lane = t & 63;
  const int wm = wid >> 2, wn = wid & 3;
  const int bid = blockIdx.x;
  const int xcd = bid & 7, idx = bid >> 3;
  const int rb = xcd * 8 + (idx >> 2);
  const int cb = idx & 3;
  const int row0 = rb * 256, col0 = cb * 256;
  const int n0 = rb * 16;
  const int b0i = cb * 4;

  const int id0 = t, id1 = 512 + t;
  const int sr0 = id0 >> 2, sg0 = id0 & 3;
  const int sr1 = id1 >> 2, sg1 = id1 & 3;
  const int soff0 = sr0 * 1024 + ((sg0 ^ ((sr0 >> 1) & 3)) << 3);
  const int soff1 = sr1 * 1024 + ((sg1 ^ ((sr1 >> 1) & 3)) << 3);
  const int sdst0 = id0 << 4, sdst1 = id1 << 4;

  const uint16_t* Ab = Ebf + ((size_t)row0 << 10);
  const uint16_t* Bb = VbfT + ((size_t)col0 << 10);

#define ISSUE(gbase, kt, h, ldsoff)                                           \
  { gload_lds16((gbase) + soff0 + (kt) * 64 + (h) * 32, smem + (ldsoff) + sdst0); \
    gload_lds16((gbase) + soff1 + (kt) * 64 + (h) * 32, smem + (ldsoff) + sdst1); }
#define BARR() { __builtin_amdgcn_s_barrier(); __builtin_amdgcn_sched_barrier(0); }
#define WAITN(N) asm volatile("s_waitcnt vmcnt(" #N ")" ::: "memory")
#define RDA(SET, BASE)                                                        \
  { _Pragma("unroll") for (int i = 0; i < 8; ++i)                             \
      SET[i] = *(const bf16x8*)(smem + (BASE) + aoff[i]); }
#define RDB(REG, BASE, J0)                                                    \
  { REG[0] = *(const bf16x8*)(smem + (BASE) + boff[(J0)]);                    \
    REG[1] = *(const bf16x8*)(smem + (BASE) + boff[(J0) + 1]); }

  int aoff[8], boff[4];
#pragma unroll
  for (int i = 0; i < 8; ++i) {
    int r = wm * 128 + i * 16 + (lane & 15);
    aoff[i] = (r * 4 + ((lane >> 4) ^ ((r >> 1) & 3))) << 4;
  }
#pragma unroll
  for (int j = 0; j < 4; ++j) {
    int r = wn * 64 + j * 16 + (lane & 15);
    boff[j] = (r * 4 + ((lane >> 4) ^ ((r >> 1) & 3))) << 4;
  }

  // ---- acc init = Lc (k depends only on lane/r; same value for all i) ----
  f32x4 acc[8][4];
  {
#pragma unroll
    for (int j = 0; j < 4; ++j) {
      const int col = wn * 64 + j * 16 + (lane & 15);
      const int bb = b0i + (col >> 6), v = col & 63;
      const float* lp = Lc + (size_t)(((bb << 4) + ((lane >> 4) << 2)) << 6) + v;
      f32x4 lc;
#pragma unroll
      for (int r = 0; r < 4; ++r) lc[r] = lp[r << 6];
#pragma unroll
      for (int i = 0; i < 8; ++i) acc[i][j] = lc;
    }
  }

  // ---- prologue: 7 half-tiles ----
  ISSUE(Ab, 0, 0, 0);
  ISSUE(Bb, 0, 0, 32768);
  ISSUE(Ab, 0, 1, 16384);
  ISSUE(Bb, 0, 1, 49152);
  ISSUE(Ab, 1, 0, 65536);
  ISSUE(Bb, 1, 0, 98304);
  ISSUE(Ab, 1, 1, 81920);

  bf16x8 AsetE[8], AsetO[8], bA[2], bB[2];
  WAITN(10);
  BARR();
  RDA(AsetE, 0);          // ph0 A (buf0.A_k0)
  RDB(bA, 32768, 0);      // ph0 B frags 0,1

#pragma unroll 1
  for (int it = 0; it < 8; ++it) {
    const int kA = it * 2, kB = kA + 1;
    const bool lastI = (it == 7);

    // ---- P0: use h0 (AsetE,bA); read bB(h0) ----
    WAITN(8);
    BARR();
    ISSUE(Bb, kB, 1, 114688);
    RDB(bB, 32768, 2);
    mfma2<0>(AsetE, bA[0], bA[1], acc);
    // ---- P1: use h0 (AsetE,bB); read A(h1)->AsetO, bA(h1) ----
    if (lastI) { WAITN(0); } else { WAITN(8); }
    BARR();
    if (!lastI) ISSUE(Ab, kA + 2, 0, 0);
    RDA(AsetO, 16384);
    RDB(bA, 49152, 0);
    mfma2<2>(AsetE, bB[0], bB[1], acc);
    // ---- P2: use h1 (AsetO,bA); read bB(h1) ----
    if (lastI) { WAITN(0); } else { WAITN(8); }
    BARR();
    if (!lastI) ISSUE(Bb, kA + 2, 0, 32768);
    RDB(bB, 49152, 2);
    mfma2<0>(AsetO, bA[0], bA[1], acc);
    // ---- P3: use h1 (AsetO,bB); read A(h2)->AsetE, bA(h2) ----
    if (lastI) { WAITN(0); } else { WAITN(8); }
    BARR();
    if (!lastI) ISSUE(Ab, kA + 2, 1, 16384);
    RDA(AsetE, 65536);
    RDB(bA, 98304, 0);
    mfma2<2>(AsetO, bB[0], bB[1], acc);
    // ---- P4: use h2 (AsetE,bA); read bB(h2) ----
    if (lastI) { WAITN(0); } else { WAITN(8); }
    BARR();
    if (!lastI) ISSUE(Bb, kA + 2, 1, 49152);
    RDB(bB, 98304, 2);
    mfma2<0>(AsetE, bA[0], bA[1], acc);
    // ---- P5: use h2 (AsetE,bB); read A(h3)->AsetO, bA(h3) ----
    if (lastI) { WAITN(0); } else { WAITN(8); }
    BARR();
    if (!lastI) ISSUE(Ab, kB + 2, 0, 65536);
    RDA(AsetO, 81920);
    RDB(bA, 114688, 0);
    mfma2<2>(AsetE, bB[0], bB[1], acc);
    // ---- P6: use h3 (AsetO,bA); read bB(h3) ----
    if (lastI) { WAITN(0); } else { WAITN(8); }
    BARR();
    if (!lastI) ISSUE(Bb, kB + 2, 0, 98304);
    RDB(bB, 114688, 2);
    mfma2<0>(AsetO, bA[0], bA[1], acc);
    // ---- P7: use h3 (AsetO,bB); read next-iter h0 ----
    if (lastI) { WAITN(0); } else { WAITN(8); }
    BARR();
    if (!lastI) {
      ISSUE(Ab, kB + 2, 1, 81920);
      RDA(AsetE, 0);
      RDB(bA, 32768, 0);
    }
    mfma2<2>(AsetO, bB[0], bB[1], acc);
  }
  __syncthreads();

  // ---- fused epilogue: 4 phases of 64 rows through LDS (Lc pre-folded) ----
  float* Cs = (float*)smem;        // [64][258]
#pragma unroll
  for (int p = 0; p < 4; ++p) {
    if (wm == (p >> 1)) {
#pragma unroll
      for (int il = 0; il < 4; ++il) {
        const int i = ((p & 1) << 2) + il;
#pragma unroll
        for (int j = 0; j < 4; ++j) {
          const int col = wn * 64 + j * 16 + (lane & 15);
#pragma unroll
          for (int r = 0; r < 4; ++r) {
            const int rl = il * 16 + ((lane >> 4) << 2) + r;
            Cs[rl * 258 + col] = acc[i][j][r];
          }
        }
      }
    }
    __syncthreads();
    {
      const int v = t & 63;
#pragma unroll
      for (int c = 0; c < 8; ++c) {
        const int combo = (wid << 3) + c;
        const int n_l = combo >> 4;
        const int b_l = (combo >> 2) & 3;
        const int h = combo & 3;
        const int n = n0 + (p << 2) + n_l;
        const int bb = b0i + b_l;
        const float* qp = Qf + (((size_t)(bb << 10) + n) << 6) + (h << 4);
        float sum = 0.f;
#pragma unroll
        for (int k = 0; k < 16; ++k)
          sum = fmaf(qp[k], Cs[((n_l << 4) + k) * 258 + (b_l << 6) + v], sum);
        out[(((size_t)(bb << 10) + n) << 8) + (h << 6) + v] = sum;
      }
    }
    __syncthreads();
  }
#undef ISSUE
#undef BARR
#undef WAITN
#undef RDA
#undef RDB
}

// ---------------------------------------------------------------------------
extern "C" void kernel_launch(void* const* d_in, const int* in_sizes, int n_in,
                              void* d_out, int out_size, void* d_ws, size_t ws_size,
                              hipStream_t stream) {
  const float* x   = (const float*)d_in[0];
  const float* Wq  = (const float*)d_in[1];
  const float* Wk  = (const float*)d_in[2];
  const float* Wv  = (const float*)d_in[3];
  const float* gq  = (const float*)d_in[4];
  const float* bq  = (const float*)d_in[5];
  const float* mq  = (const float*)d_in[6];
  const float* vq  = (const float*)d_in[7];
  const float* gv  = (const float*)d_in[8];
  const float* bv  = (const float*)d_in[9];
  const float* mv  = (const float*)d_in[10];
  const float* vvp = (const float*)d_in[11];
  const float* E   = (const float*)d_in[12];
  float* out = (float*)d_out;

  char* ws = (char*)d_ws;
  uint16_t* Ebf  = (uint16_t*)(ws);                          // 32 MB
  uint16_t* VbfT = (uint16_t*)(ws + 33554432);               //  2 MB
  float*    Qf   = (float*)(ws + 35651584);                  //  4 MB
  float*    part = (float*)(ws + 39845888);                  //  1 MB
  float*    Lc   = (float*)(ws + 40894464);                  // 64 KB
  uint16_t* WtP  = (uint16_t*)(ws + 40960000);               // 76 KB

  hipLaunchKernelGGL(econv, dim3(1024), dim3(256), 0, stream,
                     E, Ebf, Wq, Wk, Wv, WtP);
  hipLaunchKernelGGL(proj_mfma, dim3(256), dim3(256), 0, stream, x, WtP,
                     gq, bq, mq, vq, gv, bv, mv, vvp, Qf, VbfT, part);
  hipLaunchKernelGGL(lamc_reduce, dim3(64), dim3(256), 0, stream, part, Lc);
  hipLaunchKernelGGL(gemm_out, dim3(256), dim3(512), 0, stream, Ebf, VbfT, Qf, Lc, out);
}

// Round 14
// 72.021 us; speedup vs baseline: 1.7058x; 1.7058x over previous
//
#include <hip/hip_runtime.h>
#include <stdint.h>

#define EPS 1e-3f

typedef __bf16 bf16x8 __attribute__((ext_vector_type(8)));
typedef float  f32x4  __attribute__((ext_vector_type(4)));

static __device__ __forceinline__ uint16_t f2bf(float f) {
  union { __bf16 b; uint16_t u; } r; r.b = (__bf16)f; return r.u;
}
static __device__ __forceinline__ uint32_t cvt2(float lo, float hi) {
  union { __bf16 b[2]; uint32_t u; } r;
  r.b[0] = (__bf16)lo; r.b[1] = (__bf16)hi;
  return r.u;
}
static __device__ __forceinline__ void gload_lds16(const void* g, void* l) {
  __builtin_amdgcn_global_load_lds(
      (const __attribute__((address_space(1))) unsigned int*)g,
      (__attribute__((address_space(3))) unsigned int*)l, 16, 0, 0);
}

// ---------------------------------------------------------------------------
// Kernel 0: W transpose/convert prep (tiny).
// ---------------------------------------------------------------------------
__global__ __launch_bounds__(256) void wprep(
    const float* __restrict__ Wq, const float* __restrict__ Wk,
    const float* __restrict__ Wv, uint16_t* __restrict__ WtP)
{
  const int col = blockIdx.x, t = threadIdx.x;
  float val = (col < 64) ? Wq[t * 64 + col]
            : (col < 80) ? Wk[t * 16 + (col - 64)]
                         : Wv[t * 64 + (col - 80)];
  WtP[col * 264 + t] = f2bf(val);
}

// ---------------------------------------------------------------------------
// Kernel 1: MFMA projections + BN + softmax + V-transpose + lam_c partial.
// 256 blocks x 256 threads (full-GPU coverage — R10's 128-block variant
// halved CU occupancy and regressed).
// ---------------------------------------------------------------------------
__global__ __launch_bounds__(256) void proj_mfma(
    const float* __restrict__ x, const uint16_t* __restrict__ WtP,
    const float* __restrict__ gq, const float* __restrict__ bq,
    const float* __restrict__ mq, const float* __restrict__ vq,
    const float* __restrict__ gv, const float* __restrict__ bv,
    const float* __restrict__ mv, const float* __restrict__ vvp,
    float* __restrict__ Qf, uint16_t* __restrict__ VbfT,
    float* __restrict__ part)
{
  __shared__ __align__(16) char smem[111616];
  uint16_t* const xA = (uint16_t*)smem;         // [64][264] bf16
  char* const Wt = smem + 33792;                // [144][264] bf16

  const int t = threadIdx.x;
  const int wid = t >> 6, lane = t & 63;
  const int bid = blockIdx.x;
  const int b = bid >> 4, mc = bid & 15;
  const int r0 = b * 1024 + mc * 64;

#pragma unroll
  for (int i = 0; i < 19; ++i) {
    int off = (i * 256 + t) * 16;
    gload_lds16((const char*)WtP + off, Wt + off);
  }
  {
    const int row = t >> 2, ks0 = (t & 3) * 64;
    const float* src = x + (size_t)(r0 + row) * 256 + ks0;
    uint16_t* dstp = xA + row * 264 + ks0;
#pragma unroll
    for (int i = 0; i < 8; ++i) {
      float4 d0 = *(const float4*)(src + i * 8);
      float4 d1 = *(const float4*)(src + i * 8 + 4);
      uint4 q;
      q.x = cvt2(d0.x, d0.y); q.y = cvt2(d0.z, d0.w);
      q.z = cvt2(d1.x, d1.y); q.w = cvt2(d1.z, d1.w);
      *(uint4*)(dstp + i * 8) = q;
    }
  }
  __syncthreads();

  f32x4 acc[9];
#pragma unroll
  for (int f = 0; f < 9; ++f) acc[f] = f32x4{0.f, 0.f, 0.f, 0.f};
  const int arow = wid * 16 + (lane & 15);
#pragma unroll
  for (int kst = 0; kst < 8; ++kst) {
    const int sb = kst * 64 + ((lane >> 4) << 4);
    bf16x8 af = *(const bf16x8*)((const char*)xA + arow * 528 + sb);
#pragma unroll
    for (int f = 0; f < 9; ++f) {
      const int crow = f * 16 + (lane & 15);
      bf16x8 bfr = *(const bf16x8*)(Wt + crow * 528 + sb);
      acc[f] = __builtin_amdgcn_mfma_f32_16x16x32_bf16(af, bfr, acc[f], 0, 0, 0);
    }
  }

  const int cl = lane & 15;
  const int rbase = wid * 16 + ((lane >> 4) << 2);

  float qs[4], qb[4], qm[4], vs[4], vb[4], vm[4];
#pragma unroll
  for (int f = 0; f < 4; ++f) {
    const int c = f * 16 + cl;
    qs[f] = gq[c] * rsqrtf(vq[c] + EPS); qb[f] = bq[c]; qm[f] = mq[c];
    vs[f] = gv[c] * rsqrtf(vvp[c] + EPS); vb[f] = bv[c]; vm[f] = mv[c];
  }
#pragma unroll
  for (int f = 0; f < 4; ++f)
#pragma unroll
    for (int r = 0; r < 4; ++r)
      Qf[(size_t)(r0 + rbase + r) * 64 + f * 16 + cl] =
          (acc[f][r] - qm[f]) * qs[f] + qb[f];
  float ex[4];
#pragma unroll
  for (int r = 0; r < 4; ++r) {
    float kv = acc[4][r];
    float mx = kv;
#pragma unroll
    for (int d = 1; d < 16; d <<= 1) mx = fmaxf(mx, __shfl_xor(mx, d, 64));
    float e = __expf(kv - mx);
    float sm = e;
#pragma unroll
    for (int d = 1; d < 16; d <<= 1) sm += __shfl_xor(sm, d, 64);
    ex[r] = e / sm;
  }
  float vv[4][4];
#pragma unroll
  for (int f = 0; f < 4; ++f)
#pragma unroll
    for (int r = 0; r < 4; ++r)
      vv[f][r] = (acc[5 + f][r] - vm[f]) * vs[f] + vb[f];

  __syncthreads();
  float* const vt = (float*)smem;                 // [64][65] f32
  float* const ks = (float*)(smem + 64 * 65 * 4); // [64][20] f32
#pragma unroll
  for (int r = 0; r < 4; ++r) ks[(rbase + r) * 20 + cl] = ex[r];
#pragma unroll
  for (int f = 0; f < 4; ++f)
#pragma unroll
    for (int r = 0; r < 4; ++r) vt[(rbase + r) * 65 + f * 16 + cl] = vv[f][r];
  __syncthreads();

  {
    const int v = t & 63, grp = t >> 6;
#pragma unroll
    for (int h = 0; h < 2; ++h) {
      uint4 q;
      q.x = cvt2(vt[(grp * 16 + h * 8 + 0) * 65 + v], vt[(grp * 16 + h * 8 + 1) * 65 + v]);
      q.y = cvt2(vt[(grp * 16 + h * 8 + 2) * 65 + v], vt[(grp * 16 + h * 8 + 3) * 65 + v]);
      q.z = cvt2(vt[(grp * 16 + h * 8 + 4) * 65 + v], vt[(grp * 16 + h * 8 + 5) * 65 + v]);
      q.w = cvt2(vt[(grp * 16 + h * 8 + 6) * 65 + v], vt[(grp * 16 + h * 8 + 7) * 65 + v]);
      *(uint4*)&VbfT[(size_t)(b * 64 + v) * 1024 + mc * 64 + grp * 16 + h * 8] = q;
    }
  }
  {
    const int kq = t >> 6, v = t & 63;
    float a0 = 0.f, a1 = 0.f, a2 = 0.f, a3 = 0.f;
#pragma unroll 4
    for (int m = 0; m < 64; ++m) {
      float vvx = vt[m * 65 + v];
      a0 = fmaf(ks[m * 20 + kq * 4 + 0], vvx, a0);
      a1 = fmaf(ks[m * 20 + kq * 4 + 1], vvx, a1);
      a2 = fmaf(ks[m * 20 + kq * 4 + 2], vvx, a2);
      a3 = fmaf(ks[m * 20 + kq * 4 + 3], vvx, a3);
    }
    float* dst = part + ((size_t)(b * 16 + mc) << 10) + (kq * 4) * 64 + v;
    dst[0] = a0; dst[64] = a1; dst[128] = a2; dst[192] = a3;
  }
}

// Kernel 2: reduce 16 partials -> Lc[b][k][v]
__global__ __launch_bounds__(256) void lamc_reduce(const float* __restrict__ part,
                                                   float* __restrict__ Lc)
{
  const int gid = blockIdx.x * 256 + threadIdx.x;
  const int b = gid >> 10, r = gid & 1023;
  const float* p = part + ((size_t)b << 14) + r;
  float s = 0.f;
#pragma unroll
  for (int mc = 0; mc < 16; ++mc) s += p[mc << 10];
  Lc[((size_t)b << 10) + r] = s;
}

// ---------------------------------------------------------------------------
// Kernel 3: GEMM + fused epilogue — best measured structure (R10 gemm,
// 64.5 us profiled): 256x256 tile, BK=64, 8 waves (2x4), double buffer,
// prefetch-before-compute, A reg-staged from E fp32 with native cvt_pk,
// B via global_load_lds, XOR swizzle, XCD map.
// NEW: Lc folded into acc init (k = (lane>>4)*4+r is i-independent) —
// epilogue loses 256 scattered global loads (proven correct in R12).
// ---------------------------------------------------------------------------
__global__ __launch_bounds__(512, 2) void gemm_out(
    const float* __restrict__ E,        // [1024 n][1024 m][16 k] f32
    const uint16_t* __restrict__ VbfT,  // [1024 col][1024 m] bf16
    const float* __restrict__ Qf,       // [16384][64]
    const float* __restrict__ Lc,       // [16][16][64]
    float* __restrict__ out)            // [16384][256]
{
  __shared__ __align__(16) char smem[131072];
  char* const A0 = smem;
  char* const B0 = smem + 32768;
  char* const A1 = smem + 65536;
  char* const B1 = smem + 98304;

  const int t = threadIdx.x;
  const int wid = t >> 6, lane = t & 63;
  const int wm = wid >> 2, wn = wid & 3;
  const int bid = blockIdx.x;
  const int xcd = bid & 7, idx = bid >> 3;
  const int rb = xcd * 8 + (idx >> 2);   // 0..63
  const int cb = idx & 3;                // 0..3
  const int col0 = cb * 256;
  const int n0 = rb * 16;
  const int b0i = cb * 4;

  // A staging: thread -> (k-quad, m-pair, n-group)
  const int kq = t & 3;          // k*4 quad
  const int mp = (t >> 2) & 31;  // m-pair 0..31
  const int nb = t >> 7;         // 0..3
  const float* Eb = E + ((size_t)n0 << 14);

  int awoff[4][4];
#pragma unroll
  for (int it = 0; it < 4; ++it)
#pragma unroll
    for (int j = 0; j < 4; ++j) {
      int row = (it * 4 + nb) * 16 + kq * 4 + j;
      awoff[it][j] = row * 128 + ((mp * 4) ^ ((row & 7) << 4));
    }

  const uint16_t* bptr[4];
  int bdst[4];
  {
    const uint16_t* Bb = VbfT + ((size_t)col0 << 10);
#pragma unroll
    for (int it = 0; it < 4; ++it) {
      int id = it * 512 + t;
      int row = id >> 3, seg = id & 7;
      bptr[it] = Bb + (row << 10) + ((seg ^ (row & 7)) << 3);
      bdst[it] = id * 16;
    }
  }

  // ---- acc init = Lc (k depends only on lane/r; same for all i) ----
  f32x4 acc[8][4];
  {
#pragma unroll
    for (int j = 0; j < 4; ++j) {
      const int col = wn * 64 + j * 16 + (lane & 15);
      const int bb = b0i + (col >> 6), v = col & 63;
      const float* lp = Lc + (size_t)(((bb << 4) + ((lane >> 4) << 2)) << 6) + v;
      f32x4 lc;
#pragma unroll
      for (int r = 0; r < 4; ++r) lc[r] = lp[r << 6];
#pragma unroll
      for (int i = 0; i < 8; ++i) acc[i][j] = lc;
    }
  }

  float4 ra[4], rbx[4];

  // ---- prologue: tile 0 ----
#pragma unroll
  for (int it = 0; it < 4; ++it) {
    size_t base = ((size_t)(it * 4 + nb) << 14) + ((size_t)(mp * 2) << 4) + (kq << 2);
    ra[it]  = *(const float4*)(Eb + base);
    rbx[it] = *(const float4*)(Eb + base + 16);
  }
#pragma unroll
  for (int it = 0; it < 4; ++it) gload_lds16(bptr[it], B0 + bdst[it]);
#pragma unroll
  for (int it = 0; it < 4; ++it) {
    const float* da = (const float*)&ra[it];
    const float* db = (const float*)&rbx[it];
#pragma unroll
    for (int j = 0; j < 4; ++j)
      *(uint32_t*)(A0 + awoff[it][j]) = cvt2(da[j], db[j]);
  }
  __syncthreads();

  // ---- main loop: 16 K-tiles of 64 ----
#pragma unroll 1
  for (int kt = 0; kt < 16; ++kt) {
    char* Ac = (kt & 1) ? A1 : A0;
    char* Bc = (kt & 1) ? B1 : B0;
    char* An = (kt & 1) ? A0 : A1;
    char* Bn = (kt & 1) ? B0 : B1;
    if (kt < 15) {
      const int m0n = (kt + 1) * 64;
#pragma unroll
      for (int it = 0; it < 4; ++it) {
        size_t base = ((size_t)(it * 4 + nb) << 14) +
                      ((size_t)(m0n + mp * 2) << 4) + (kq << 2);
        ra[it]  = *(const float4*)(Eb + base);
        rbx[it] = *(const float4*)(Eb + base + 16);
      }
#pragma unroll
      for (int it = 0; it < 4; ++it) gload_lds16(bptr[it] + m0n, Bn + bdst[it]);
    }
    __builtin_amdgcn_s_setprio(1);
#pragma unroll
    for (int kk = 0; kk < 2; ++kk) {
      bf16x8 a[8], b[4];
      const int s = kk * 4 + (lane >> 4);
#pragma unroll
      for (int i = 0; i < 8; ++i) {
        int row = wm * 128 + i * 16 + (lane & 15);
        a[i] = *(const bf16x8*)(Ac + row * 128 + ((s ^ (row & 7)) << 4));
      }
#pragma unroll
      for (int j = 0; j < 4; ++j) {
        int row = wn * 64 + j * 16 + (lane & 15);
        b[j] = *(const bf16x8*)(Bc + row * 128 + ((s ^ (row & 7)) << 4));
      }
#pragma unroll
      for (int i = 0; i < 8; ++i)
#pragma unroll
        for (int j = 0; j < 4; ++j)
          acc[i][j] = __builtin_amdgcn_mfma_f32_16x16x32_bf16(a[i], b[j], acc[i][j], 0, 0, 0);
    }
    __builtin_amdgcn_s_setprio(0);
    if (kt < 15) {
#pragma unroll
      for (int it = 0; it < 4; ++it) {
        const float* da = (const float*)&ra[it];
        const float* db = (const float*)&rbx[it];
#pragma unroll
        for (int j = 0; j < 4; ++j)
          *(uint32_t*)(An + awoff[it][j]) = cvt2(da[j], db[j]);
      }
    }
    __syncthreads();
  }

  // ---- fused epilogue: 4 phases of 64 rows through LDS (Lc pre-folded) ----
  float* Cs = (float*)smem;        // [64][258]
#pragma unroll
  for (int p = 0; p < 4; ++p) {
    if (wm == (p >> 1)) {
#pragma unroll
      for (int il = 0; il < 4; ++il) {
        const int i = ((p & 1) << 2) + il;
#pragma unroll
        for (int j = 0; j < 4; ++j) {
          const int col = wn * 64 + j * 16 + (lane & 15);
#pragma unroll
          for (int r = 0; r < 4; ++r) {
            const int rl = il * 16 + ((lane >> 4) << 2) + r;
            Cs[rl * 258 + col] = acc[i][j][r];
          }
        }
      }
    }
    __syncthreads();
    {
      const int v = t & 63;
#pragma unroll
      for (int c = 0; c < 8; ++c) {
        const int combo = (wid << 3) + c;               // 0..63
        const int n_l = combo >> 4;                     // 0..3
        const int b_l = (combo >> 2) & 3;               // 0..3
        const int h = combo & 3;
        const int n = n0 + (p << 2) + n_l;
        const int bb = b0i + b_l;
        const float* qp = Qf + (((size_t)(bb << 10) + n) << 6) + (h << 4);
        float sum = 0.f;
#pragma unroll
        for (int k = 0; k < 16; ++k)
          sum = fmaf(qp[k], Cs[((n_l << 4) + k) * 258 + (b_l << 6) + v], sum);
        out[(((size_t)(bb << 10) + n) << 8) + (h << 6) + v] = sum;
      }
    }
    __syncthreads();
  }
}

// ---------------------------------------------------------------------------
extern "C" void kernel_launch(void* const* d_in, const int* in_sizes, int n_in,
                              void* d_out, int out_size, void* d_ws, size_t ws_size,
                              hipStream_t stream) {
  const float* x   = (const float*)d_in[0];
  const float* Wq  = (const float*)d_in[1];
  const float* Wk  = (const float*)d_in[2];
  const float* Wv  = (const float*)d_in[3];
  const float* gq  = (const float*)d_in[4];
  const float* bq  = (const float*)d_in[5];
  const float* mq  = (const float*)d_in[6];
  const float* vq  = (const float*)d_in[7];
  const float* gv  = (const float*)d_in[8];
  const float* bv  = (const float*)d_in[9];
  const float* mv  = (const float*)d_in[10];
  const float* vvp = (const float*)d_in[11];
  const float* E   = (const float*)d_in[12];
  float* out = (float*)d_out;

  char* ws = (char*)d_ws;
  uint16_t* VbfT = (uint16_t*)(ws);                             //  2 MB
  float*    Qf   = (float*)(ws + (size_t)(2 << 20));            //  4 MB
  float*    part = (float*)(ws + (size_t)(6 << 20));            //  1 MB
  float*    Lc   = (float*)(ws + (size_t)(7 << 20));            // 64 KB
  uint16_t* WtP  = (uint16_t*)(ws + (size_t)(7 << 20) + 65536); // 76 KB

  hipLaunchKernelGGL(wprep, dim3(144), dim3(256), 0, stream, Wq, Wk, Wv, WtP);
  hipLaunchKernelGGL(proj_mfma, dim3(256), dim3(256), 0, stream, x, WtP,
                     gq, bq, mq, vq, gv, bv, mv, vvp, Qf, VbfT, part);
  hipLaunchKernelGGL(lamc_reduce, dim3(64), dim3(256), 0, stream, part, Lc);
  hipLaunchKernelGGL(gemm_out, dim3(256), dim3(512), 0, stream, E, VbfT, Qf, Lc, out);
}

// Round 15
// 67.398 us; speedup vs baseline: 1.8228x; 1.0686x over previous
//
#include <hip/hip_runtime.h>
#include <stdint.h>

#define EPS 1e-3f

typedef __bf16 bf16x8 __attribute__((ext_vector_type(8)));
typedef float  f32x4  __attribute__((ext_vector_type(4)));

static __device__ __forceinline__ uint16_t f2bf(float f) {
  union { __bf16 b; uint16_t u; } r; r.b = (__bf16)f; return r.u;
}
static __device__ __forceinline__ uint32_t cvt2(float lo, float hi) {
  union { __bf16 b[2]; uint32_t u; } r;
  r.b[0] = (__bf16)lo; r.b[1] = (__bf16)hi;
  return r.u;
}
static __device__ __forceinline__ void gload_lds16(const void* g, void* l) {
  __builtin_amdgcn_global_load_lds(
      (const __attribute__((address_space(1))) unsigned int*)g,
      (__attribute__((address_space(3))) unsigned int*)l, 16, 0, 0);
}

// ---------------------------------------------------------------------------
// Kernel 0: W transpose/convert prep (tiny).
// ---------------------------------------------------------------------------
__global__ __launch_bounds__(256) void wprep(
    const float* __restrict__ Wq, const float* __restrict__ Wk,
    const float* __restrict__ Wv, uint16_t* __restrict__ WtP)
{
  const int col = blockIdx.x, t = threadIdx.x;
  float val = (col < 64) ? Wq[t * 64 + col]
            : (col < 80) ? Wk[t * 16 + (col - 64)]
                         : Wv[t * 64 + (col - 80)];
  WtP[col * 264 + t] = f2bf(val);
}

// ---------------------------------------------------------------------------
// Kernel 1: MFMA projections + BN + softmax + V-transpose + lam_c partial.
// (unchanged — R14 passing)
// ---------------------------------------------------------------------------
__global__ __launch_bounds__(256) void proj_mfma(
    const float* __restrict__ x, const uint16_t* __restrict__ WtP,
    const float* __restrict__ gq, const float* __restrict__ bq,
    const float* __restrict__ mq, const float* __restrict__ vq,
    const float* __restrict__ gv, const float* __restrict__ bv,
    const float* __restrict__ mv, const float* __restrict__ vvp,
    float* __restrict__ Qf, uint16_t* __restrict__ VbfT,
    float* __restrict__ part)
{
  __shared__ __align__(16) char smem[111616];
  uint16_t* const xA = (uint16_t*)smem;         // [64][264] bf16
  char* const Wt = smem + 33792;                // [144][264] bf16

  const int t = threadIdx.x;
  const int wid = t >> 6, lane = t & 63;
  const int bid = blockIdx.x;
  const int b = bid >> 4, mc = bid & 15;
  const int r0 = b * 1024 + mc * 64;

#pragma unroll
  for (int i = 0; i < 19; ++i) {
    int off = (i * 256 + t) * 16;
    gload_lds16((const char*)WtP + off, Wt + off);
  }
  {
    const int row = t >> 2, ks0 = (t & 3) * 64;
    const float* src = x + (size_t)(r0 + row) * 256 + ks0;
    uint16_t* dstp = xA + row * 264 + ks0;
#pragma unroll
    for (int i = 0; i < 8; ++i) {
      float4 d0 = *(const float4*)(src + i * 8);
      float4 d1 = *(const float4*)(src + i * 8 + 4);
      uint4 q;
      q.x = cvt2(d0.x, d0.y); q.y = cvt2(d0.z, d0.w);
      q.z = cvt2(d1.x, d1.y); q.w = cvt2(d1.z, d1.w);
      *(uint4*)(dstp + i * 8) = q;
    }
  }
  __syncthreads();

  f32x4 acc[9];
#pragma unroll
  for (int f = 0; f < 9; ++f) acc[f] = f32x4{0.f, 0.f, 0.f, 0.f};
  const int arow = wid * 16 + (lane & 15);
#pragma unroll
  for (int kst = 0; kst < 8; ++kst) {
    const int sb = kst * 64 + ((lane >> 4) << 4);
    bf16x8 af = *(const bf16x8*)((const char*)xA + arow * 528 + sb);
#pragma unroll
    for (int f = 0; f < 9; ++f) {
      const int crow = f * 16 + (lane & 15);
      bf16x8 bfr = *(const bf16x8*)(Wt + crow * 528 + sb);
      acc[f] = __builtin_amdgcn_mfma_f32_16x16x32_bf16(af, bfr, acc[f], 0, 0, 0);
    }
  }

  const int cl = lane & 15;
  const int rbase = wid * 16 + ((lane >> 4) << 2);

  float qs[4], qb[4], qm[4], vs[4], vb[4], vm[4];
#pragma unroll
  for (int f = 0; f < 4; ++f) {
    const int c = f * 16 + cl;
    qs[f] = gq[c] * rsqrtf(vq[c] + EPS); qb[f] = bq[c]; qm[f] = mq[c];
    vs[f] = gv[c] * rsqrtf(vvp[c] + EPS); vb[f] = bv[c]; vm[f] = mv[c];
  }
#pragma unroll
  for (int f = 0; f < 4; ++f)
#pragma unroll
    for (int r = 0; r < 4; ++r)
      Qf[(size_t)(r0 + rbase + r) * 64 + f * 16 + cl] =
          (acc[f][r] - qm[f]) * qs[f] + qb[f];
  float ex[4];
#pragma unroll
  for (int r = 0; r < 4; ++r) {
    float kv = acc[4][r];
    float mx = kv;
#pragma unroll
    for (int d = 1; d < 16; d <<= 1) mx = fmaxf(mx, __shfl_xor(mx, d, 64));
    float e = __expf(kv - mx);
    float sm = e;
#pragma unroll
    for (int d = 1; d < 16; d <<= 1) sm += __shfl_xor(sm, d, 64);
    ex[r] = e / sm;
  }
  float vv[4][4];
#pragma unroll
  for (int f = 0; f < 4; ++f)
#pragma unroll
    for (int r = 0; r < 4; ++r)
      vv[f][r] = (acc[5 + f][r] - vm[f]) * vs[f] + vb[f];

  __syncthreads();
  float* const vt = (float*)smem;                 // [64][65] f32
  float* const ks = (float*)(smem + 64 * 65 * 4); // [64][20] f32
#pragma unroll
  for (int r = 0; r < 4; ++r) ks[(rbase + r) * 20 + cl] = ex[r];
#pragma unroll
  for (int f = 0; f < 4; ++f)
#pragma unroll
    for (int r = 0; r < 4; ++r) vt[(rbase + r) * 65 + f * 16 + cl] = vv[f][r];
  __syncthreads();

  {
    const int v = t & 63, grp = t >> 6;
#pragma unroll
    for (int h = 0; h < 2; ++h) {
      uint4 q;
      q.x = cvt2(vt[(grp * 16 + h * 8 + 0) * 65 + v], vt[(grp * 16 + h * 8 + 1) * 65 + v]);
      q.y = cvt2(vt[(grp * 16 + h * 8 + 2) * 65 + v], vt[(grp * 16 + h * 8 + 3) * 65 + v]);
      q.z = cvt2(vt[(grp * 16 + h * 8 + 4) * 65 + v], vt[(grp * 16 + h * 8 + 5) * 65 + v]);
      q.w = cvt2(vt[(grp * 16 + h * 8 + 6) * 65 + v], vt[(grp * 16 + h * 8 + 7) * 65 + v]);
      *(uint4*)&VbfT[(size_t)(b * 64 + v) * 1024 + mc * 64 + grp * 16 + h * 8] = q;
    }
  }
  {
    const int kq = t >> 6, v = t & 63;
    float a0 = 0.f, a1 = 0.f, a2 = 0.f, a3 = 0.f;
#pragma unroll 4
    for (int m = 0; m < 64; ++m) {
      float vvx = vt[m * 65 + v];
      a0 = fmaf(ks[m * 20 + kq * 4 + 0], vvx, a0);
      a1 = fmaf(ks[m * 20 + kq * 4 + 1], vvx, a1);
      a2 = fmaf(ks[m * 20 + kq * 4 + 2], vvx, a2);
      a3 = fmaf(ks[m * 20 + kq * 4 + 3], vvx, a3);
    }
    float* dst = part + ((size_t)(b * 16 + mc) << 10) + (kq * 4) * 64 + v;
    dst[0] = a0; dst[64] = a1; dst[128] = a2; dst[192] = a3;
  }
}

// Kernel 2: reduce 16 partials -> Lc[b][k][v]
__global__ __launch_bounds__(256) void lamc_reduce(const float* __restrict__ part,
                                                   float* __restrict__ Lc)
{
  const int gid = blockIdx.x * 256 + threadIdx.x;
  const int b = gid >> 10, r = gid & 1023;
  const float* p = part + ((size_t)b << 14) + r;
  float s = 0.f;
#pragma unroll
  for (int mc = 0; mc < 16; ++mc) s += p[mc << 10];
  Lc[((size_t)b << 10) + r] = s;
}

// ---------------------------------------------------------------------------
// Kernel 3: GEMM + fused epilogue — R14 structure, but 16 WAVES (1024 thr,
// 4x4 wave grid, 64x64 per wave -> acc[4][4] = 64 AGPR).  Target <=128
// total regs/wave -> 4 waves/SIMD (vs R14's 256-reg/2-wave limit).
// Per-thread staging halves.  Everything else identical (double buffer,
// prefetch-before-compute, reg-staged A + cvt_pk, B gload_lds, XOR swizzle,
// XCD map, Lc folded into acc init).
// ---------------------------------------------------------------------------
__global__ __launch_bounds__(1024, 4) void gemm_out(
    const float* __restrict__ E,        // [1024 n][1024 m][16 k] f32
    const uint16_t* __restrict__ VbfT,  // [1024 col][1024 m] bf16
    const float* __restrict__ Qf,       // [16384][64]
    const float* __restrict__ Lc,       // [16][16][64]
    float* __restrict__ out)            // [16384][256]
{
  __shared__ __align__(16) char smem[131072];
  char* const A0 = smem;
  char* const B0 = smem + 32768;
  char* const A1 = smem + 65536;
  char* const B1 = smem + 98304;

  const int t = threadIdx.x;
  const int wid = t >> 6, lane = t & 63;
  const int wm = wid >> 2, wn = wid & 3;        // 4x4 wave grid
  const int bid = blockIdx.x;
  const int xcd = bid & 7, idx = bid >> 3;
  const int rb = xcd * 8 + (idx >> 2);   // 0..63
  const int cb = idx & 3;                // 0..3
  const int col0 = cb * 256;
  const int n0 = rb * 16;
  const int b0i = cb * 4;

  // A staging: thread -> (k-quad, m-pair, n-subgroup of 8)
  const int kq = t & 3;          // k*4 quad
  const int mp = (t >> 2) & 31;  // m-pair 0..31
  const int nb = t >> 7;         // 0..7 ; n-group = it*8 + nb
  const float* Eb = E + ((size_t)n0 << 14);

  int awoff[2][4];
#pragma unroll
  for (int it = 0; it < 2; ++it)
#pragma unroll
    for (int j = 0; j < 4; ++j) {
      int row = (it * 8 + nb) * 16 + kq * 4 + j;
      awoff[it][j] = row * 128 + ((mp * 4) ^ ((row & 7) << 4));
    }

  const uint16_t* bptr[2];
  int bdst[2];
  {
    const uint16_t* Bb = VbfT + ((size_t)col0 << 10);
#pragma unroll
    for (int it = 0; it < 2; ++it) {
      int id = it * 1024 + t;
      int row = id >> 3, seg = id & 7;
      bptr[it] = Bb + (row << 10) + ((seg ^ (row & 7)) << 3);
      bdst[it] = id * 16;
    }
  }

  // ---- acc init = Lc (k = (lane>>4)*4+r is i-independent; bb = b0i+wn) ----
  f32x4 acc[4][4];
  {
    const int bb = b0i + wn;
    const float* lb = Lc + (size_t)(((bb << 4) + ((lane >> 4) << 2)) << 6);
#pragma unroll
    for (int j = 0; j < 4; ++j) {
      const int v = j * 16 + (lane & 15);
      f32x4 lc;
#pragma unroll
      for (int r = 0; r < 4; ++r) lc[r] = lb[(r << 6) + v];
#pragma unroll
      for (int i = 0; i < 4; ++i) acc[i][j] = lc;
    }
  }

  float4 ra[2], rbx[2];

  // ---- prologue: tile 0 ----
#pragma unroll
  for (int it = 0; it < 2; ++it) {
    size_t base = ((size_t)(it * 8 + nb) << 14) + ((size_t)(mp * 2) << 4) + (kq << 2);
    ra[it]  = *(const float4*)(Eb + base);
    rbx[it] = *(const float4*)(Eb + base + 16);
  }
#pragma unroll
  for (int it = 0; it < 2; ++it) gload_lds16(bptr[it], B0 + bdst[it]);
#pragma unroll
  for (int it = 0; it < 2; ++it) {
    const float* da = (const float*)&ra[it];
    const float* db = (const float*)&rbx[it];
#pragma unroll
    for (int j = 0; j < 4; ++j)
      *(uint32_t*)(A0 + awoff[it][j]) = cvt2(da[j], db[j]);
  }
  __syncthreads();

  // ---- main loop: 16 K-tiles of 64 ----
#pragma unroll 1
  for (int kt = 0; kt < 16; ++kt) {
    char* Ac = (kt & 1) ? A1 : A0;
    char* Bc = (kt & 1) ? B1 : B0;
    char* An = (kt & 1) ? A0 : A1;
    char* Bn = (kt & 1) ? B0 : B1;
    if (kt < 15) {
      const int m0n = (kt + 1) * 64;
#pragma unroll
      for (int it = 0; it < 2; ++it) {
        size_t base = ((size_t)(it * 8 + nb) << 14) +
                      ((size_t)(m0n + mp * 2) << 4) + (kq << 2);
        ra[it]  = *(const float4*)(Eb + base);
        rbx[it] = *(const float4*)(Eb + base + 16);
      }
#pragma unroll
      for (int it = 0; it < 2; ++it) gload_lds16(bptr[it] + m0n, Bn + bdst[it]);
    }
    __builtin_amdgcn_s_setprio(1);
#pragma unroll
    for (int kk = 0; kk < 2; ++kk) {
      bf16x8 a[4], b[4];
      const int s = kk * 4 + (lane >> 4);
#pragma unroll
      for (int i = 0; i < 4; ++i) {
        int row = wm * 64 + i * 16 + (lane & 15);
        a[i] = *(const bf16x8*)(Ac + row * 128 + ((s ^ (row & 7)) << 4));
      }
#pragma unroll
      for (int j = 0; j < 4; ++j) {
        int row = wn * 64 + j * 16 + (lane & 15);
        b[j] = *(const bf16x8*)(Bc + row * 128 + ((s ^ (row & 7)) << 4));
      }
#pragma unroll
      for (int i = 0; i < 4; ++i)
#pragma unroll
        for (int j = 0; j < 4; ++j)
          acc[i][j] = __builtin_amdgcn_mfma_f32_16x16x32_bf16(a[i], b[j], acc[i][j], 0, 0, 0);
    }
    __builtin_amdgcn_s_setprio(0);
    if (kt < 15) {
#pragma unroll
      for (int it = 0; it < 2; ++it) {
        const float* da = (const float*)&ra[it];
        const float* db = (const float*)&rbx[it];
#pragma unroll
        for (int j = 0; j < 4; ++j)
          *(uint32_t*)(An + awoff[it][j]) = cvt2(da[j], db[j]);
      }
    }
    __syncthreads();
  }

  // ---- fused epilogue: 4 phases of 64 rows through LDS (Lc pre-folded) ----
  float* Cs = (float*)smem;        // [64][258]
#pragma unroll
  for (int p = 0; p < 4; ++p) {
    if (wm == p) {
#pragma unroll
      for (int i = 0; i < 4; ++i) {
#pragma unroll
        for (int j = 0; j < 4; ++j) {
          const int col = wn * 64 + j * 16 + (lane & 15);
#pragma unroll
          for (int r = 0; r < 4; ++r) {
            const int rl = i * 16 + ((lane >> 4) << 2) + r;
            Cs[rl * 258 + col] = acc[i][j][r];
          }
        }
      }
    }
    __syncthreads();
    {
      const int v = t & 63;
#pragma unroll
      for (int c = 0; c < 4; ++c) {
        const int combo = ((t >> 6) << 2) + c;          // 0..63
        const int n_l = combo >> 4;                     // 0..3
        const int b_l = (combo >> 2) & 3;               // 0..3
        const int h = combo & 3;
        const int n = n0 + (p << 2) + n_l;
        const int bb = b0i + b_l;
        const float* qp = Qf + (((size_t)(bb << 10) + n) << 6) + (h << 4);
        float sum = 0.f;
#pragma unroll
        for (int k = 0; k < 16; ++k)
          sum = fmaf(qp[k], Cs[((n_l << 4) + k) * 258 + (b_l << 6) + v], sum);
        out[(((size_t)(bb << 10) + n) << 8) + (h << 6) + v] = sum;
      }
    }
    __syncthreads();
  }
}

// ---------------------------------------------------------------------------
extern "C" void kernel_launch(void* const* d_in, const int* in_sizes, int n_in,
                              void* d_out, int out_size, void* d_ws, size_t ws_size,
                              hipStream_t stream) {
  const float* x   = (const float*)d_in[0];
  const float* Wq  = (const float*)d_in[1];
  const float* Wk  = (const float*)d_in[2];
  const float* Wv  = (const float*)d_in[3];
  const float* gq  = (const float*)d_in[4];
  const float* bq  = (const float*)d_in[5];
  const float* mq  = (const float*)d_in[6];
  const float* vq  = (const float*)d_in[7];
  const float* gv  = (const float*)d_in[8];
  const float* bv  = (const float*)d_in[9];
  const float* mv  = (const float*)d_in[10];
  const float* vvp = (const float*)d_in[11];
  const float* E   = (const float*)d_in[12];
  float* out = (float*)d_out;

  char* ws = (char*)d_ws;
  uint16_t* VbfT = (uint16_t*)(ws);                             //  2 MB
  float*    Qf   = (float*)(ws + (size_t)(2 << 20));            //  4 MB
  float*    part = (float*)(ws + (size_t)(6 << 20));            //  1 MB
  float*    Lc   = (float*)(ws + (size_t)(7 << 20));            // 64 KB
  uint16_t* WtP  = (uint16_t*)(ws + (size_t)(7 << 20) + 65536); // 76 KB

  hipLaunchKernelGGL(wprep, dim3(144), dim3(256), 0, stream, Wq, Wk, Wv, WtP);
  hipLaunchKernelGGL(proj_mfma, dim3(256), dim3(256), 0, stream, x, WtP,
                     gq, bq, mq, vq, gv, bv, mv, vvp, Qf, VbfT, part);
  hipLaunchKernelGGL(lamc_reduce, dim3(64), dim3(256), 0, stream, part, Lc);
  hipLaunchKernelGGL(gemm_out, dim3(256), dim3(1024), 0, stream, E, VbfT, Qf, Lc, out);
}